// Round 4
// baseline (548.593 us; speedup 1.0000x reference)
//
#include <hip/hip_runtime.h>

// LightPrompt inner_structure_update (dense form), MI355X gfx950.
// Outputs (f32, concat): x[4096,128] | adj[4096,4096] | edge_attr[4096,4096,4]
// Write-bound floor ~50us (337.6 MB out @ ~6.9 TB/s). dot = tok@tok.T via f32
// vector FMA (no fp32-input MFMA on CDNA4; bf16 MFMA rejected: mask-flip risk
// at the sigmoid threshold).
//
// R4 vs R3 (97.6us): LDS-read pipe was the top term (~82us: 2 B/FMA at 4x4
// thread tile). Now 128x128 block tile, 8x8 thread tile -> 1 B/FMA (~41us),
// split-K=32 (LDS 36.9KB, 4 blocks/CU), grid 1024 = 4/CU exactly.

typedef float f32x4 __attribute__((ext_vector_type(4)));

static constexpr int Tn = 4096;
static constexpr int Dm = 128;
static constexpr int En = 4;
static constexpr float THRE = 0.55f;
static constexpr float SLOPE = 0.01f;

#define BT 128   // block tile (i and j)
#define KS 32    // k split
#define LDK 36   // 32 + 4 pad: row stride 144B (16B-aligned, 9 banks-of-4 per row)

__global__ __launch_bounds__(256, 4) void lp_fused(const float* __restrict__ tokens,
                                                   const float* __restrict__ edge_token,
                                                   float* __restrict__ out) {
    __shared__ float As[BT][LDK];
    __shared__ float Bs[BT][LDK];

    const int tid = threadIdx.x;
    const int i0 = blockIdx.y << 7;
    const int j0 = blockIdx.x << 7;

    // x output = tokens verbatim (131072 float4): first 512 of 1024 blocks.
    const int bid = blockIdx.y * (Tn / BT) + blockIdx.x;
    if (bid < 512) {
        reinterpret_cast<f32x4*>(out)[bid * 256 + tid] =
            reinterpret_cast<const f32x4*>(tokens)[bid * 256 + tid];
    }

    const int tx = tid & 15;   // col group: j = j0 + tx + 16*c, c=0..7
    const int ty = tid >> 4;   // row group: i = i0 + ty + 16*r, r=0..7

    float acc[8][8];
#pragma unroll
    for (int r = 0; r < 8; ++r)
#pragma unroll
        for (int c = 0; c < 8; ++c) acc[r][c] = 0.0f;

#pragma unroll
    for (int kp = 0; kp < Dm / KS; ++kp) {
        const int kbase = kp * KS;
        // Stage 128 rows x 32 floats of A and B: 1024 float4 each, 4/thread.
        // 8 threads cover one row's 128B slice -> coalesced.
        {
#pragma unroll
            for (int p = 0; p < 4; ++p) {
                const int f = (p << 8) + tid;      // 0..1023
                const int row = f >> 3;
                const int c4 = (f & 7) << 2;
                *reinterpret_cast<f32x4*>(&As[row][c4]) =
                    *reinterpret_cast<const f32x4*>(tokens + (size_t)(i0 + row) * Dm + kbase + c4);
                *reinterpret_cast<f32x4*>(&Bs[row][c4]) =
                    *reinterpret_cast<const f32x4*>(tokens + (size_t)(j0 + row) * Dm + kbase + c4);
            }
        }
        __syncthreads();

#pragma unroll
        for (int k = 0; k < KS; k += 4) {
            f32x4 b4[8];
#pragma unroll
            for (int c = 0; c < 8; ++c)
                b4[c] = *reinterpret_cast<const f32x4*>(&Bs[tx + (c << 4)][k]);
#pragma unroll
            for (int r = 0; r < 8; ++r) {
                const f32x4 a4 = *reinterpret_cast<const f32x4*>(&As[ty + (r << 4)][k]);
#pragma unroll
                for (int c = 0; c < 8; ++c)
                    acc[r][c] = fmaf(a4.x, b4[c].x,
                                fmaf(a4.y, b4[c].y,
                                fmaf(a4.z, b4[c].z,
                                fmaf(a4.w, b4[c].w, acc[r][c]))));
            }
        }
        __syncthreads();
    }

    const float e0 = edge_token[0];
    const float e1 = edge_token[1];
    const float e2 = edge_token[2];
    const float e3 = edge_token[3];

    float* __restrict__ adj  = out + (size_t)Tn * Dm;
    float* __restrict__ attr = adj + (size_t)Tn * Tn;

#pragma unroll
    for (int r = 0; r < 8; ++r) {
        const int i = i0 + ty + (r << 4);
#pragma unroll
        for (int c = 0; c < 8; ++c) {
            const int j = j0 + tx + (c << 4);
            const float d = acc[r][c];
            const float sim = 1.0f / (1.0f + __expf(-d));
            const float m = (sim >= THRE) ? 1.0f : 0.0f;
            __builtin_nontemporal_store(sim * m, adj + (size_t)i * Tn + j);
            f32x4 at;
            float v;
            v = d * e0; at.x = (v > 0.0f ? v : SLOPE * v) * m;
            v = d * e1; at.y = (v > 0.0f ? v : SLOPE * v) * m;
            v = d * e2; at.z = (v > 0.0f ? v : SLOPE * v) * m;
            v = d * e3; at.w = (v > 0.0f ? v : SLOPE * v) * m;
            __builtin_nontemporal_store(at, reinterpret_cast<f32x4*>(attr + ((size_t)i * Tn + j) * En));
        }
    }
}

extern "C" void kernel_launch(void* const* d_in, const int* in_sizes, int n_in,
                              void* d_out, int out_size, void* d_ws, size_t ws_size,
                              hipStream_t stream) {
    const float* tokens     = (const float*)d_in[0];  // [1,4096,128] f32
    const float* edge_token = (const float*)d_in[1];  // [1,4] f32
    float* out = (float*)d_out;

    hipLaunchKernelGGL(lp_fused, dim3(Tn / BT, Tn / BT), dim3(256), 0, stream,
                       tokens, edge_token, out);
}

// Round 5
// 91.707 us; speedup vs baseline: 5.9820x; 5.9820x over previous
//
#include <hip/hip_runtime.h>

// LightPrompt inner_structure_update (dense form), MI355X gfx950.
// Outputs (f32, concat): x[4096,128] | adj[4096,4096] | edge_attr[4096,4096,4]
// Write-bound floor ~50us (345.6 MB out @ ~6.9 TB/s fill-rate). dot = tok@tok.T
// via f32 vector FMA (no fp32-input MFMA on CDNA4; bf16 MFMA rejected:
// mask-flip risk at the sigmoid threshold on near-boundary diagonal dots).
//
// R5 vs R4 (548us, SPILLED): R4's acc[8][8]=64 + b4[8]=32 exceeded the 64-reg
// budget the allocator chose under __launch_bounds__(256,4) -> 2.7 GB scratch
// traffic (FETCH 863MB, WRITE 2.18GB). R5: 8x4 thread tile (acc=32, live~85),
// plain __launch_bounds__(256), 128x64 block tile, KS=32 (LDS 27.6KB).
// LDS-read pipe ~20-25us (was ~60-80 in R3's 4x4), under the store floor.

typedef float f32x4 __attribute__((ext_vector_type(4)));

static constexpr int Tn = 4096;
static constexpr int Dm = 128;
static constexpr int En = 4;
static constexpr float THRE = 0.55f;
static constexpr float SLOPE = 0.01f;

#define BM 128   // block rows (i)
#define BN 64    // block cols (j)
#define KS 32    // k split
#define LDK 36   // 32 + 4 pad: row stride 144B, bank groups spread by 4/row

__global__ __launch_bounds__(256) void lp_fused(const float* __restrict__ tokens,
                                                const float* __restrict__ edge_token,
                                                float* __restrict__ out) {
    __shared__ float As[BM][LDK];
    __shared__ float Bs[BN][LDK];

    const int tid = threadIdx.x;
    const int i0 = blockIdx.y * BM;
    const int j0 = blockIdx.x * BN;

    // x output = tokens verbatim (131072 float4): first 512 of 2048 blocks.
    const int bid = blockIdx.y * (Tn / BN) + blockIdx.x;
    if (bid < 512) {
        reinterpret_cast<f32x4*>(out)[bid * 256 + tid] =
            reinterpret_cast<const f32x4*>(tokens)[bid * 256 + tid];
    }

    const int tx = tid & 15;   // j = j0 + tx + 16*c, c=0..3
    const int ty = tid >> 4;   // i = i0 + ty + 16*r, r=0..7

    float acc[8][4];
#pragma unroll
    for (int r = 0; r < 8; ++r)
#pragma unroll
        for (int c = 0; c < 4; ++c) acc[r][c] = 0.0f;

#pragma unroll
    for (int kp = 0; kp < Dm / KS; ++kp) {
        const int kbase = kp * KS;
        // Stage A (128x32 f): 1024 f32x4, 4/thread; B (64x32 f): 512, 2/thread.
        // 8 threads cover one row's 128B slice -> coalesced; LDS writes uniform
        // across bank groups (4*(row+chunk) mod 32).
#pragma unroll
        for (int p = 0; p < 4; ++p) {
            const int f = (p << 8) + tid;
            const int row = f >> 3;
            const int c4 = (f & 7) << 2;
            *reinterpret_cast<f32x4*>(&As[row][c4]) =
                *reinterpret_cast<const f32x4*>(tokens + (size_t)(i0 + row) * Dm + kbase + c4);
        }
#pragma unroll
        for (int p = 0; p < 2; ++p) {
            const int f = (p << 8) + tid;
            const int row = f >> 3;
            const int c4 = (f & 7) << 2;
            *reinterpret_cast<f32x4*>(&Bs[row][c4]) =
                *reinterpret_cast<const f32x4*>(tokens + (size_t)(j0 + row) * Dm + kbase + c4);
        }
        __syncthreads();

        // Bs reads: 2-way bank alias + 4-way ty broadcast; As reads: 16-lane
        // broadcast (4 unique rows/wave) -> both near LDS minimum cost.
#pragma unroll
        for (int k = 0; k < KS; k += 4) {
            f32x4 b4[4];
#pragma unroll
            for (int c = 0; c < 4; ++c)
                b4[c] = *reinterpret_cast<const f32x4*>(&Bs[tx + (c << 4)][k]);
#pragma unroll
            for (int r = 0; r < 8; ++r) {
                const f32x4 a4 = *reinterpret_cast<const f32x4*>(&As[ty + (r << 4)][k]);
#pragma unroll
                for (int c = 0; c < 4; ++c)
                    acc[r][c] = fmaf(a4.x, b4[c].x,
                                fmaf(a4.y, b4[c].y,
                                fmaf(a4.z, b4[c].z,
                                fmaf(a4.w, b4[c].w, acc[r][c]))));
            }
        }
        __syncthreads();
    }

    const float e0 = edge_token[0];
    const float e1 = edge_token[1];
    const float e2 = edge_token[2];
    const float e3 = edge_token[3];

    float* __restrict__ adj  = out + (size_t)Tn * Dm;
    float* __restrict__ attr = adj + (size_t)Tn * Tn;

#pragma unroll
    for (int r = 0; r < 8; ++r) {
        const int i = i0 + ty + (r << 4);
#pragma unroll
        for (int c = 0; c < 4; ++c) {
            const int j = j0 + tx + (c << 4);
            const float d = acc[r][c];
            const float sim = 1.0f / (1.0f + __expf(-d));
            const float m = (sim >= THRE) ? 1.0f : 0.0f;
            __builtin_nontemporal_store(sim * m, adj + (size_t)i * Tn + j);
            f32x4 at;
            float v;
            v = d * e0; at.x = (v > 0.0f ? v : SLOPE * v) * m;
            v = d * e1; at.y = (v > 0.0f ? v : SLOPE * v) * m;
            v = d * e2; at.z = (v > 0.0f ? v : SLOPE * v) * m;
            v = d * e3; at.w = (v > 0.0f ? v : SLOPE * v) * m;
            __builtin_nontemporal_store(at, reinterpret_cast<f32x4*>(attr + ((size_t)i * Tn + j) * En));
        }
    }
}

extern "C" void kernel_launch(void* const* d_in, const int* in_sizes, int n_in,
                              void* d_out, int out_size, void* d_ws, size_t ws_size,
                              hipStream_t stream) {
    const float* tokens     = (const float*)d_in[0];  // [1,4096,128] f32
    const float* edge_token = (const float*)d_in[1];  // [1,4] f32
    float* out = (float*)d_out;

    hipLaunchKernelGGL(lp_fused, dim3(Tn / BN, Tn / BM), dim3(256), 0, stream,
                       tokens, edge_token, out);
}